// Round 2
// baseline (199.692 us; speedup 1.0000x reference)
//
#include <hip/hip_runtime.h>
#include <hip/hip_bf16.h>

// Shapes (fixed by the reference)
#define BB 2
#define SS 2048
#define HH 1024
#define NH 16
#define HD 64
#define MM (BB * SS)          // 4096 rows of x
#define N_QKV (3 * HH)        // 3072
#define KK HH                 // 1024

typedef __attribute__((ext_vector_type(8))) short short8;
typedef __attribute__((ext_vector_type(4))) float floatx4;
typedef __attribute__((ext_vector_type(16))) float floatx16;

#define MFMA16(a, b, c) __builtin_amdgcn_mfma_f32_16x16x32_bf16(a, b, c, 0, 0, 0)
#define MFMA32(a, b, c) __builtin_amdgcn_mfma_f32_32x32x16_bf16(a, b, c, 0, 0, 0)

__device__ __forceinline__ unsigned short f2bf(float f) {
  unsigned int u = __builtin_bit_cast(unsigned int, f);
  u += 0x7FFFu + ((u >> 16) & 1u);   // RNE
  return (unsigned short)(u >> 16);
}

// Raw v_exp_f32 — scores are bounded, underflow-to-0 harmless.
__device__ __forceinline__ float fexp2(float x) {
#if __has_builtin(__builtin_amdgcn_exp2f)
  return __builtin_amdgcn_exp2f(x);
#else
  float r; asm("v_exp_f32 %0, %1" : "=v"(r) : "v"(x)); return r;
#endif
}

// pack2 WITHOUT rounding fixup for exp results (attn path) — keep bit-identical
// to the passing kernels.
__device__ __forceinline__ unsigned int pack2e(float lo, float hi) {
  unsigned int a = __builtin_bit_cast(unsigned int, lo) + 0x8000u;
  unsigned int b = __builtin_bit_cast(unsigned int, hi) + 0x8000u;
  return __builtin_amdgcn_perm(b, a, 0x07060302u);
}

// v_cvt_pk_bf16_f32: 2 f32 -> packed 2x bf16 (lo | hi<<16), RNE — bit-identical
// to the old pack2 (3 VALU) at 1 VALU. No builtin on gfx950; inline asm (m240).
__device__ __forceinline__ unsigned int cvtpk(float lo, float hi) {
  unsigned int r;
  asm("v_cvt_pk_bf16_f32 %0, %1, %2" : "=v"(r) : "v"(lo), "v"(hi));
  return r;
}

// convert 8 f32 (two float4) -> 8 bf16 packed in a uint4 (RNE)
__device__ __forceinline__ uint4 cvt8pk(float4 lo, float4 hi) {
  uint4 u;
  u.x = cvtpk(lo.x, lo.y);
  u.y = cvtpk(lo.z, lo.w);
  u.z = cvtpk(hi.x, hi.y);
  u.w = cvtpk(hi.z, hi.w);
  return u;
}

// Async global->LDS DMA, 16 B per lane. LDS dest must be the WAVE-UNIFORM base;
// HW writes base + lane*16 (m104). Global source is per-lane.
__device__ __forceinline__ void gload_lds16(const void* g, void* l) {
  __builtin_amdgcn_global_load_lds((const __attribute__((address_space(1))) void*)g,
                                   (__attribute__((address_space(3))) void*)l,
                                   16, 0, 0);
}

// ---------------------------------------------------------------- cast
// Generic f32 -> bf16 (RNE, identical rounding to the old in-GEMM pack2).
// Each thread converts 8 contiguous elements. Grid sized exactly per tensor.
__global__ __launch_bounds__(256) void cast_g(const float* __restrict__ s,
                                              unsigned short* __restrict__ d) {
  size_t i = (size_t)blockIdx.x * 256 + threadIdx.x;
  float4 lo = *(const float4*)(s + i * 8);
  float4 hi = *(const float4*)(s + i * 8 + 4);
  *(uint4*)(d + i * 8) = cvt8pk(lo, hi);
}

// ---------------------------------------------------------------- QKV GEMM
// m97-style staging: A always via global_load_lds (bf16 xb, pre-cast).
// BPRE=1: B also pre-cast bf16, via global_load_lds (pure-DMA staging).
// BPRE=0: B reg-staged from f32 qkv_w with v_cvt_pk conversion (fits 32 MiB ws).
// LDS layout + fragment reads identical to the previous passing kernel.
template <int BPRE>
__global__ __launch_bounds__(256) void gemm_qkv(const unsigned short* __restrict__ Xb,
                                                const float* __restrict__ Wf,
                                                const unsigned short* __restrict__ Wb,
                                                unsigned short* __restrict__ qb,
                                                unsigned short* __restrict__ kb,
                                                unsigned short* __restrict__ vtb) {
  __shared__ __attribute__((aligned(16))) unsigned short As[128 * 32];
  __shared__ __attribute__((aligned(16))) unsigned short Bs[128 * 32];
  const int tid = threadIdx.x;
  const int wave = tid >> 6, lane = tid & 63;
  const int quad = lane >> 4, lc = lane & 15;
  const int m0 = blockIdx.y * 128, n0 = blockIdx.x * 128;
  const int wm = (wave >> 1) * 64, wn = (wave & 1) * 64;
  const int sr = tid >> 2, sc = (tid & 3) * 8;   // staging row / col-chunk

  floatx4 acc[4][4];
#pragma unroll
  for (int i = 0; i < 4; i++)
#pragma unroll
    for (int j = 0; j < 4; j++) acc[i][j] = (floatx4){0.f, 0.f, 0.f, 0.f};

  // per-lane global sources; wave-uniform LDS dests (HW adds lane*16)
  const unsigned short* Axp = Xb + (size_t)(m0 + sr) * KK + sc;
  unsigned short* AsD = As + wave * 512;   // bytes: wave*1024, +lane*16 by HW
  unsigned short* BsD = Bs + wave * 512;

  const unsigned short* Bxp = nullptr;
  const float* Bg = nullptr;
  float4 b0l, b0h, b1l, b1h;
  unsigned short* BsW = Bs + wave * 512 + lane * 8;
  if constexpr (BPRE) {
    Bxp = Wb + (size_t)(n0 + sr) * KK + sc;
  } else {
    Bg = Wf + (size_t)(n0 + sr) * KK + sc;
    b0l = *(const float4*)(Bg);                    b0h = *(const float4*)(Bg + 4);
    b1l = *(const float4*)(Bg + (size_t)64 * KK);  b1h = *(const float4*)(Bg + (size_t)64 * KK + 4);
  }

  for (int it = 0; it < KK / 32; ++it) {
    const int k0 = it * 32;
    __syncthreads();                       // previous iteration's LDS reads done
    gload_lds16(Axp + k0, AsD);
    gload_lds16(Axp + (size_t)64 * KK + k0, AsD + 2048);
    if constexpr (BPRE) {
      gload_lds16(Bxp + k0, BsD);
      gload_lds16(Bxp + (size_t)64 * KK + k0, BsD + 2048);
    } else {
      *(uint4*)(BsW) = cvt8pk(b0l, b0h);
      *(uint4*)(BsW + 2048) = cvt8pk(b1l, b1h);
      if (it + 1 < KK / 32) {
        b0l = *(const float4*)(Bg + k0 + 32);                    b0h = *(const float4*)(Bg + k0 + 36);
        b1l = *(const float4*)(Bg + k0 + 32 + (size_t)64 * KK);  b1h = *(const float4*)(Bg + k0 + 36 + (size_t)64 * KK);
      }
    }
    __syncthreads();                       // drains vmcnt(0): DMA tile visible
    short8 af[4], bf[4];
#pragma unroll
    for (int i = 0; i < 4; i++) {
      af[i] = *(const short8*)(As + (wm + i * 16 + lc) * 32 + quad * 8);
      bf[i] = *(const short8*)(Bs + (wn + i * 16 + lc) * 32 + quad * 8);
    }
#pragma unroll
    for (int i = 0; i < 4; i++)
#pragma unroll
      for (int j = 0; j < 4; j++) acc[i][j] = MFMA16(af[i], bf[j], acc[i][j]);
  }

  const float QSCALE = 0.125f * 1.44269504f;   // 1/sqrt(64) * log2(e)
#pragma unroll
  for (int j = 0; j < 4; j++) {
    int n = n0 + wn + j * 16 + lc;
#pragma unroll
    for (int i = 0; i < 4; i++) {
      int mbase = m0 + wm + i * 16 + quad * 4;
      int b = mbase >> 11;
      int s0 = mbase & 2047;
      if (n < HH) {                 // Q, pre-scale
        int h = n >> 6, d = n & 63;
#pragma unroll
        for (int r = 0; r < 4; r++)
          qb[(((size_t)(b * NH + h) * SS + s0 + r) * HD) + d] = f2bf(acc[i][j][r] * QSCALE);
      } else if (n < 2 * HH) {      // K
        int n2 = n - HH; int h = n2 >> 6, d = n2 & 63;
#pragma unroll
        for (int r = 0; r < 4; r++)
          kb[(((size_t)(b * NH + h) * SS + s0 + r) * HD) + d] = f2bf(acc[i][j][r]);
      } else {                      // V -> transposed [b][h][d][s]
        int n2 = n - 2 * HH; int h = n2 >> 6, d = n2 & 63;
        ushort4 p;
        p.x = f2bf(acc[i][j][0]); p.y = f2bf(acc[i][j][1]);
        p.z = f2bf(acc[i][j][2]); p.w = f2bf(acc[i][j][3]);
        *(ushort4*)(vtb + ((size_t)(b * NH + h) * HD + d) * SS + s0) = p;
      }
    }
  }
}

// ---------------------------------------------------------------- flash attention
// Round-11 exact (passed 4 rounds, ~54 µs): S^T = K*Q^T core, in-register P.
__device__ __forceinline__ int co(int row, int c16) {   // ushort offset of (row, chunk)
  return row * 64 + ((c16 ^ ((row ^ (row >> 3)) & 7)) << 3);
}

__global__ __launch_bounds__(256, 2) void attn_kernel(const unsigned short* __restrict__ qg,
                                                      const unsigned short* __restrict__ kg,
                                                      const unsigned short* __restrict__ vtg,
                                                      unsigned short* __restrict__ og) {
  __shared__ __attribute__((aligned(16))) unsigned short Sall[16384];
  unsigned short* Qs = Sall;            // 128 rows x 64
  unsigned short* Ks = Sall + 8192;     //  64 rows x 64 (keys x d)
  unsigned short* Vs = Sall + 12288;    //  64 rows x 64 ([d][key])

  const int tid = threadIdx.x;
  const int w = tid >> 6, lane = tid & 63;
  const int hl = lane >> 5, c = lane & 31;
  const int q0 = blockIdx.x * 128;
  const int head = blockIdx.y, b = blockIdx.z;

  const unsigned short* qbase = qg + (size_t)(b * NH + head) * SS * HD;
  const unsigned short* kbase = kg + (size_t)(b * NH + head) * SS * HD;
  const unsigned short* vbase = vtg + (size_t)(b * NH + head) * HD * SS;

  {
    int row = tid >> 3, cc = tid & 7;
#pragma unroll
    for (int s = 0; s < 4; s++)
      *(uint4*)(Qs + co(row + 32 * s, cc)) =
          *(const uint4*)(qbase + (size_t)(q0 + row + 32 * s) * HD + cc * 8);
  }

  const int frow = tid >> 3, fc = tid & 7;
  uint4 k0r = *(const uint4*)(kbase + (size_t)frow * HD + fc * 8);
  uint4 k1r = *(const uint4*)(kbase + (size_t)(frow + 32) * HD + fc * 8);
  uint4 v0r = *(const uint4*)(vbase + (size_t)frow * SS + fc * 8);
  uint4 v1r = *(const uint4*)(vbase + (size_t)(frow + 32) * SS + fc * 8);

  floatx16 oacc0, oacc1, lacc;
#pragma unroll
  for (int i = 0; i < 16; i++) { oacc0[i] = 0.f; oacc1[i] = 0.f; lacc[i] = 0.f; }

  short8 ones;
#pragma unroll
  for (int i = 0; i < 8; i++) ones[i] = (short)0x3F80;   // bf16 1.0

  short8 qa[4];

  for (int kt = 0; kt < SS; kt += 64) {
    __syncthreads();
    *(uint4*)(Ks + co(frow, fc)) = k0r;
    *(uint4*)(Ks + co(frow + 32, fc)) = k1r;
    *(uint4*)(Vs + co(frow, fc)) = v0r;
    *(uint4*)(Vs + co(frow + 32, fc)) = v1r;
    if (kt + 64 < SS) {
      k0r = *(const uint4*)(kbase + (size_t)(kt + 64 + frow) * HD + fc * 8);
      k1r = *(const uint4*)(kbase + (size_t)(kt + 96 + frow) * HD + fc * 8);
      v0r = *(const uint4*)(vbase + (size_t)frow * SS + kt + 64 + fc * 8);
      v1r = *(const uint4*)(vbase + (size_t)(frow + 32) * SS + kt + 64 + fc * 8);
    }
    __syncthreads();

    if (kt == 0) {
#pragma unroll
      for (int ks = 0; ks < 4; ks++)
        qa[ks] = *(const short8*)(Qs + co(w * 32 + c, ks * 2 + hl));
    }

    floatx16 sacc0, sacc1;
#pragma unroll
    for (int i = 0; i < 16; i++) { sacc0[i] = 0.f; sacc1[i] = 0.f; }
#pragma unroll
    for (int ks = 0; ks < 4; ks++) {
      short8 ka0 = *(const short8*)(Ks + co(c, ks * 2 + hl));
      short8 ka1 = *(const short8*)(Ks + co(32 + c, ks * 2 + hl));
      sacc0 = MFMA32(ka0, qa[ks], sacc0);
      sacc1 = MFMA32(ka1, qa[ks], sacc1);
    }

    short8 pb[4];
#pragma unroll
    for (int kb = 0; kb < 4; kb++) {
      const floatx16& s = (kb < 2) ? sacc0 : sacc1;
      int base = (kb & 1) * 8;
      unsigned int u0 = pack2e(fexp2(s[base + 0]), fexp2(s[base + 1]));
      unsigned int u1 = pack2e(fexp2(s[base + 2]), fexp2(s[base + 3]));
      unsigned int u2 = pack2e(fexp2(s[base + 4]), fexp2(s[base + 5]));
      unsigned int u3 = pack2e(fexp2(s[base + 6]), fexp2(s[base + 7]));
      uint4 u = {u0, u1, u2, u3};
      pb[kb] = __builtin_bit_cast(short8, u);
    }

#pragma unroll
    for (int kb = 0; kb < 4; kb++) {
      uint2 lo0 = *(const uint2*)(Vs + co(c, 2 * kb) + 4 * hl);
      uint2 hi0 = *(const uint2*)(Vs + co(c, 2 * kb + 1) + 4 * hl);
      uint4 a0 = {lo0.x, lo0.y, hi0.x, hi0.y};
      short8 va0 = __builtin_bit_cast(short8, a0);
      uint2 lo1 = *(const uint2*)(Vs + co(32 + c, 2 * kb) + 4 * hl);
      uint2 hi1 = *(const uint2*)(Vs + co(32 + c, 2 * kb + 1) + 4 * hl);
      uint4 a1 = {lo1.x, lo1.y, hi1.x, hi1.y};
      short8 va1 = __builtin_bit_cast(short8, a1);
      oacc0 = MFMA32(va0, pb[kb], oacc0);
      oacc1 = MFMA32(va1, pb[kb], oacc1);
      lacc = MFMA32(ones, pb[kb], lacc);
    }
  }

  __syncthreads();
  unsigned short* sc = Sall + w * 2176;
  float inv = 1.0f / lacc[0];
#pragma unroll
  for (int t = 0; t < 8; t++) {
    int d0 = ((2 * t) & 3) + 8 * (t >> 1) + 4 * hl;
    *(unsigned int*)(sc + c * 68 + d0) = pack2e(oacc0[2 * t] * inv, oacc0[2 * t + 1] * inv);
    *(unsigned int*)(sc + c * 68 + 32 + d0) = pack2e(oacc1[2 * t] * inv, oacc1[2 * t + 1] * inv);
  }
  {
    int ql = lane >> 1, hf = lane & 1;
    size_t row = (size_t)(b * SS + q0 + w * 32 + ql);
    unsigned short* dst = og + row * HH + head * 64 + hf * 32;
    const unsigned short* srcp = sc + ql * 68 + hf * 32;
#pragma unroll
    for (int s = 0; s < 4; s++) {
      uint2 a = *(const uint2*)(srcp + s * 8);
      uint2 bq = *(const uint2*)(srcp + s * 8 + 4);
      uint4 v = {a.x, a.y, bq.x, bq.y};
      *(uint4*)(dst + s * 8) = v;
    }
  }
}

// ---------------------------------------------------------------- out projection
// 128m x 64n tiles; A (bf16 ao) and pre-cast bf16 B both via global_load_lds.
__global__ __launch_bounds__(256) void gemm_out(const unsigned short* __restrict__ A,
                                                const unsigned short* __restrict__ Wb,
                                                float* __restrict__ C) {
  __shared__ __attribute__((aligned(16))) unsigned short As[128 * 32];  // 8 KB
  __shared__ __attribute__((aligned(16))) unsigned short Bs[64 * 32];   // 4 KB
  const int tid = threadIdx.x;
  const int wave = tid >> 6, lane = tid & 63;
  const int quad = lane >> 4, lc = lane & 15;
  const int m0 = blockIdx.y * 128, n0 = blockIdx.x * 64;
  const int wm = (wave >> 1) * 64, wn = (wave & 1) * 32;
  const int sr = tid >> 2, sc = (tid & 3) * 8;

  floatx4 acc[4][2];
#pragma unroll
  for (int i = 0; i < 4; i++)
#pragma unroll
    for (int j = 0; j < 2; j++) acc[i][j] = (floatx4){0.f, 0.f, 0.f, 0.f};

  const unsigned short* Axp = A + (size_t)(m0 + sr) * KK + sc;
  const unsigned short* Bxp = Wb + (size_t)(n0 + sr) * KK + sc;
  unsigned short* AsD = As + wave * 512;
  unsigned short* BsD = Bs + wave * 512;

  for (int it = 0; it < KK / 32; ++it) {
    const int k0 = it * 32;
    __syncthreads();
    gload_lds16(Axp + k0, AsD);
    gload_lds16(Axp + (size_t)64 * KK + k0, AsD + 2048);
    gload_lds16(Bxp + k0, BsD);
    __syncthreads();
    short8 af[4], bf[2];
#pragma unroll
    for (int i = 0; i < 4; i++)
      af[i] = *(const short8*)(As + (wm + i * 16 + lc) * 32 + quad * 8);
#pragma unroll
    for (int j = 0; j < 2; j++)
      bf[j] = *(const short8*)(Bs + (wn + j * 16 + lc) * 32 + quad * 8);
#pragma unroll
    for (int i = 0; i < 4; i++)
#pragma unroll
      for (int j = 0; j < 2; j++) acc[i][j] = MFMA16(af[i], bf[j], acc[i][j]);
  }

#pragma unroll
  for (int i = 0; i < 4; i++)
#pragma unroll
    for (int j = 0; j < 2; j++) {
      int m = m0 + wm + i * 16 + quad * 4;
      int n = n0 + wn + j * 16 + lc;
#pragma unroll
      for (int r = 0; r < 4; r++) C[(size_t)(m + r) * HH + n] = acc[i][j][r];
    }
}

// ---------------------------------------------------------------- launch
extern "C" void kernel_launch(void* const* d_in, const int* in_sizes, int n_in,
                              void* d_out, int out_size, void* d_ws, size_t ws_size,
                              hipStream_t stream) {
  const float* x = (const float*)d_in[0];        // [2,2048,1024]
  const float* qkv_w = (const float*)d_in[1];    // [3072,1024]
  const float* out_w = (const float*)d_in[2];    // [1024,1024]
  float* out = (float*)d_out;                    // [2,2048,1024] fp32

  char* ws = (char*)d_ws;
  unsigned short* qb  = (unsigned short*)(ws + 0);          //  8 MiB [B][h][S][64]
  unsigned short* kb  = (unsigned short*)(ws + 8388608);    //  8 MiB [B][h][S][64]
  unsigned short* vtb = (unsigned short*)(ws + 16777216);   //  8 MiB [B][h][64][S]
  unsigned short* xb  = (unsigned short*)(ws + 25165824);   //  8 MiB bf16 x (dead after gemm_qkv)
  unsigned short* ao  = xb;                                 //  aliases xb (attn writes after)
  unsigned short* wob = qb;                                 //  bf16 out_w, aliases qb (dead after attn)

  // Optional extra region for pre-cast qkv_w (pure-DMA staging in gemm_qkv).
  const bool big = ws_size >= 40ull * 1024 * 1024;
  unsigned short* w1b = big ? (unsigned short*)(ws + 33554432) : nullptr;  // 6 MiB bf16 qkv_w

  cast_g<<<dim3(MM * KK / 2048), dim3(256), 0, stream>>>(x, xb);           // 2048 blocks
  if (big) {
    cast_g<<<dim3(N_QKV * KK / 2048), dim3(256), 0, stream>>>(qkv_w, w1b); // 1536 blocks
    gemm_qkv<1><<<dim3(N_QKV / 128, MM / 128), dim3(256), 0, stream>>>(xb, qkv_w, w1b, qb, kb, vtb);
  } else {
    gemm_qkv<0><<<dim3(N_QKV / 128, MM / 128), dim3(256), 0, stream>>>(xb, qkv_w, nullptr, qb, kb, vtb);
  }
  attn_kernel<<<dim3(SS / 128, NH, BB), dim3(256), 0, stream>>>(qb, kb, vtb, ao);
  cast_g<<<dim3(HH * KK / 2048), dim3(256), 0, stream>>>(out_w, wob);      // 512 blocks
  gemm_out<<<dim3(HH / 64, MM / 128), dim3(256), 0, stream>>>(ao, wob, out);
}

// Round 3
// 192.596 us; speedup vs baseline: 1.0368x; 1.0368x over previous
//
#include <hip/hip_runtime.h>
#include <hip/hip_bf16.h>

// Shapes (fixed by the reference)
#define BB 2
#define SS 2048
#define HH 1024
#define NH 16
#define HD 64
#define MM (BB * SS)          // 4096 rows of x
#define N_QKV (3 * HH)        // 3072
#define KK HH                 // 1024

typedef __attribute__((ext_vector_type(8))) short short8;
typedef __attribute__((ext_vector_type(4))) float floatx4;
typedef __attribute__((ext_vector_type(16))) float floatx16;

#define MFMA16(a, b, c) __builtin_amdgcn_mfma_f32_16x16x32_bf16(a, b, c, 0, 0, 0)
#define MFMA32(a, b, c) __builtin_amdgcn_mfma_f32_32x32x16_bf16(a, b, c, 0, 0, 0)

__device__ __forceinline__ unsigned short f2bf(float f) {
  unsigned int u = __builtin_bit_cast(unsigned int, f);
  u += 0x7FFFu + ((u >> 16) & 1u);   // RNE
  return (unsigned short)(u >> 16);
}

// Raw v_exp_f32 — scores are bounded, underflow-to-0 harmless.
__device__ __forceinline__ float fexp2(float x) {
#if __has_builtin(__builtin_amdgcn_exp2f)
  return __builtin_amdgcn_exp2f(x);
#else
  float r; asm("v_exp_f32 %0, %1" : "=v"(r) : "v"(x)); return r;
#endif
}

// pack2 WITHOUT rounding fixup for exp results (attn path) — keep bit-identical
// to the passing kernels.
__device__ __forceinline__ unsigned int pack2e(float lo, float hi) {
  unsigned int a = __builtin_bit_cast(unsigned int, lo) + 0x8000u;
  unsigned int b = __builtin_bit_cast(unsigned int, hi) + 0x8000u;
  return __builtin_amdgcn_perm(b, a, 0x07060302u);
}

// v_cvt_pk_bf16_f32: 2 f32 -> packed 2x bf16, RNE — 1 VALU. Inline asm (m240).
__device__ __forceinline__ unsigned int cvtpk(float lo, float hi) {
  unsigned int r;
  asm("v_cvt_pk_bf16_f32 %0, %1, %2" : "=v"(r) : "v"(lo), "v"(hi));
  return r;
}

// convert 8 f32 (two float4) -> 8 bf16 packed in a uint4 (RNE)
__device__ __forceinline__ uint4 cvt8pk(float4 lo, float4 hi) {
  uint4 u;
  u.x = cvtpk(lo.x, lo.y);
  u.y = cvtpk(lo.z, lo.w);
  u.z = cvtpk(hi.x, hi.y);
  u.w = cvtpk(hi.z, hi.w);
  return u;
}

// Async global->LDS DMA, 16 B per lane. LDS dest must be the WAVE-UNIFORM base;
// HW writes base + lane*16 (m104). Global source is per-lane.
__device__ __forceinline__ void gload_lds16(const void* g, void* l) {
  __builtin_amdgcn_global_load_lds((const __attribute__((address_space(1))) void*)g,
                                   (__attribute__((address_space(3))) void*)l,
                                   16, 0, 0);
}

// ---------------------------------------------------------------- casts
// Fused f32 -> bf16 for x (region 0) and qkv_w (region 1). Grid = 3584 blocks.
__global__ __launch_bounds__(256) void cast_xw(const float* __restrict__ x,
                                               const float* __restrict__ w1,
                                               unsigned short* __restrict__ xb,
                                               unsigned short* __restrict__ w1b) {
  const int NX = MM * KK / 8;          // 524288
  int i = blockIdx.x * 256 + threadIdx.x;
  const float* s; unsigned short* d; int o;
  if (i < NX) { s = x;  d = xb;  o = i; }
  else        { s = w1; d = w1b; o = i - NX; }
  float4 lo = *(const float4*)(s + (size_t)o * 8);
  float4 hi = *(const float4*)(s + (size_t)o * 8 + 4);
  *(uint4*)(d + (size_t)o * 8) = cvt8pk(lo, hi);
}

// Generic single-tensor cast (out_w, and x in the small-ws fallback).
__global__ __launch_bounds__(256) void cast_g(const float* __restrict__ s,
                                              unsigned short* __restrict__ d) {
  size_t i = (size_t)blockIdx.x * 256 + threadIdx.x;
  float4 lo = *(const float4*)(s + i * 8);
  float4 hi = *(const float4*)(s + i * 8 + 4);
  *(uint4*)(d + i * 8) = cvt8pk(lo, hi);
}

// ---------------------------------------------------------------- QKV GEMM (dbuf DMA)
// T3-minimum 2-phase: double-buffered LDS, STAGE(t+1) issued BEFORE compute(t),
// counted s_waitcnt vmcnt(4) (tile t landed, t+1 still in flight), raw barriers.
__global__ __launch_bounds__(256) void gemm_qkv_dma(const unsigned short* __restrict__ Xb,
                                                    const unsigned short* __restrict__ Wb,
                                                    unsigned short* __restrict__ qb,
                                                    unsigned short* __restrict__ kb,
                                                    unsigned short* __restrict__ vtb) {
  __shared__ __attribute__((aligned(16))) unsigned short As[2][128 * 32];  // 2 x 8 KB
  __shared__ __attribute__((aligned(16))) unsigned short Bs[2][128 * 32];  // 2 x 8 KB
  const int tid = threadIdx.x;
  const int wave = tid >> 6;
  const int lane = tid & 63;
  const int quad = lane >> 4, lc = lane & 15;
  const int m0 = blockIdx.y * 128, n0 = blockIdx.x * 128;
  const int wm = (wave >> 1) * 64, wn = (wave & 1) * 64;
  const int sr = tid >> 2, sc = (tid & 3) * 8;   // staging row / col-chunk

  floatx4 acc[4][4];
#pragma unroll
  for (int i = 0; i < 4; i++)
#pragma unroll
    for (int j = 0; j < 4; j++) acc[i][j] = (floatx4){0.f, 0.f, 0.f, 0.f};

  const unsigned short* Axp = Xb + (size_t)(m0 + sr) * KK + sc;
  const unsigned short* Bxp = Wb + (size_t)(n0 + sr) * KK + sc;

#define STAGEQ(buf, k0)                                               \
  do {                                                                \
    gload_lds16(Axp + (k0), &As[buf][wave * 512]);                    \
    gload_lds16(Axp + (size_t)64 * KK + (k0), &As[buf][wave * 512 + 2048]); \
    gload_lds16(Bxp + (k0), &Bs[buf][wave * 512]);                    \
    gload_lds16(Bxp + (size_t)64 * KK + (k0), &Bs[buf][wave * 512 + 2048]); \
  } while (0)

  STAGEQ(0, 0);   // prologue: tile 0 in flight

  const int NIT = KK / 32;   // 32
  for (int it = 0; it < NIT; ++it) {
    const int cb = it & 1;
    if (it + 1 < NIT) {
      STAGEQ(cb ^ 1, (it + 1) * 32);                 // issue next tile first
      asm volatile("s_waitcnt vmcnt(4)" ::: "memory");  // tile it landed; next 4 in flight
    } else {
      asm volatile("s_waitcnt vmcnt(0)" ::: "memory");
    }
    __builtin_amdgcn_s_barrier();                    // tile it visible to all waves
    __builtin_amdgcn_sched_barrier(0);
    short8 af[4], bfr[4];
#pragma unroll
    for (int i = 0; i < 4; i++) {
      af[i]  = *(const short8*)(&As[cb][(wm + i * 16 + lc) * 32 + quad * 8]);
      bfr[i] = *(const short8*)(&Bs[cb][(wn + i * 16 + lc) * 32 + quad * 8]);
    }
#pragma unroll
    for (int i = 0; i < 4; i++)
#pragma unroll
      for (int j = 0; j < 4; j++) acc[i][j] = MFMA16(af[i], bfr[j], acc[i][j]);
    __builtin_amdgcn_sched_barrier(0);
    __builtin_amdgcn_s_barrier();                    // all reads of buf cb done -> safe to overwrite next iter
  }
#undef STAGEQ

  const float QSCALE = 0.125f * 1.44269504f;   // 1/sqrt(64) * log2(e)
#pragma unroll
  for (int j = 0; j < 4; j++) {
    int n = n0 + wn + j * 16 + lc;
#pragma unroll
    for (int i = 0; i < 4; i++) {
      int mbase = m0 + wm + i * 16 + quad * 4;
      int b = mbase >> 11;
      int s0 = mbase & 2047;
      if (n < HH) {                 // Q, pre-scale
        int h = n >> 6, d = n & 63;
#pragma unroll
        for (int r = 0; r < 4; r++)
          qb[(((size_t)(b * NH + h) * SS + s0 + r) * HD) + d] = f2bf(acc[i][j][r] * QSCALE);
      } else if (n < 2 * HH) {      // K
        int n2 = n - HH; int h = n2 >> 6, d = n2 & 63;
#pragma unroll
        for (int r = 0; r < 4; r++)
          kb[(((size_t)(b * NH + h) * SS + s0 + r) * HD) + d] = f2bf(acc[i][j][r]);
      } else {                      // V -> transposed [b][h][d][s]
        int n2 = n - 2 * HH; int h = n2 >> 6, d = n2 & 63;
        ushort4 p;
        p.x = f2bf(acc[i][j][0]); p.y = f2bf(acc[i][j][1]);
        p.z = f2bf(acc[i][j][2]); p.w = f2bf(acc[i][j][3]);
        *(ushort4*)(vtb + ((size_t)(b * NH + h) * HD + d) * SS + s0) = p;
      }
    }
  }
}

// ---------------------------------------------------------------- QKV GEMM (f32-B fallback)
// Round-0/2 structure: A via DMA from bf16 xb, B reg-staged f32 + cvt. Only used
// when the workspace is too small for the pre-cast qkv_w region.
__global__ __launch_bounds__(256) void gemm_qkv_f32(const unsigned short* __restrict__ Xb,
                                                    const float* __restrict__ Wf,
                                                    unsigned short* __restrict__ qb,
                                                    unsigned short* __restrict__ kb,
                                                    unsigned short* __restrict__ vtb) {
  __shared__ __attribute__((aligned(16))) unsigned short As[128 * 32];
  __shared__ __attribute__((aligned(16))) unsigned short Bs[128 * 32];
  const int tid = threadIdx.x;
  const int wave = tid >> 6, lane = tid & 63;
  const int quad = lane >> 4, lc = lane & 15;
  const int m0 = blockIdx.y * 128, n0 = blockIdx.x * 128;
  const int wm = (wave >> 1) * 64, wn = (wave & 1) * 64;
  const int sr = tid >> 2, sc = (tid & 3) * 8;

  floatx4 acc[4][4];
#pragma unroll
  for (int i = 0; i < 4; i++)
#pragma unroll
    for (int j = 0; j < 4; j++) acc[i][j] = (floatx4){0.f, 0.f, 0.f, 0.f};

  const unsigned short* Axp = Xb + (size_t)(m0 + sr) * KK + sc;
  unsigned short* AsD = As + wave * 512;
  const float* Bg = Wf + (size_t)(n0 + sr) * KK + sc;
  unsigned short* BsW = Bs + wave * 512 + lane * 8;
  float4 b0l = *(const float4*)(Bg),                    b0h = *(const float4*)(Bg + 4);
  float4 b1l = *(const float4*)(Bg + (size_t)64 * KK),  b1h = *(const float4*)(Bg + (size_t)64 * KK + 4);

  for (int it = 0; it < KK / 32; ++it) {
    const int k0 = it * 32;
    __syncthreads();
    gload_lds16(Axp + k0, AsD);
    gload_lds16(Axp + (size_t)64 * KK + k0, AsD + 2048);
    *(uint4*)(BsW) = cvt8pk(b0l, b0h);
    *(uint4*)(BsW + 2048) = cvt8pk(b1l, b1h);
    if (it + 1 < KK / 32) {
      b0l = *(const float4*)(Bg + k0 + 32);                    b0h = *(const float4*)(Bg + k0 + 36);
      b1l = *(const float4*)(Bg + k0 + 32 + (size_t)64 * KK);  b1h = *(const float4*)(Bg + k0 + 36 + (size_t)64 * KK);
    }
    __syncthreads();
    short8 af[4], bfr[4];
#pragma unroll
    for (int i = 0; i < 4; i++) {
      af[i]  = *(const short8*)(As + (wm + i * 16 + lc) * 32 + quad * 8);
      bfr[i] = *(const short8*)(Bs + (wn + i * 16 + lc) * 32 + quad * 8);
    }
#pragma unroll
    for (int i = 0; i < 4; i++)
#pragma unroll
      for (int j = 0; j < 4; j++) acc[i][j] = MFMA16(af[i], bfr[j], acc[i][j]);
  }

  const float QSCALE = 0.125f * 1.44269504f;
#pragma unroll
  for (int j = 0; j < 4; j++) {
    int n = n0 + wn + j * 16 + lc;
#pragma unroll
    for (int i = 0; i < 4; i++) {
      int mbase = m0 + wm + i * 16 + quad * 4;
      int b = mbase >> 11;
      int s0 = mbase & 2047;
      if (n < HH) {
        int h = n >> 6, d = n & 63;
#pragma unroll
        for (int r = 0; r < 4; r++)
          qb[(((size_t)(b * NH + h) * SS + s0 + r) * HD) + d] = f2bf(acc[i][j][r] * QSCALE);
      } else if (n < 2 * HH) {
        int n2 = n - HH; int h = n2 >> 6, d = n2 & 63;
#pragma unroll
        for (int r = 0; r < 4; r++)
          kb[(((size_t)(b * NH + h) * SS + s0 + r) * HD) + d] = f2bf(acc[i][j][r]);
      } else {
        int n2 = n - 2 * HH; int h = n2 >> 6, d = n2 & 63;
        ushort4 p;
        p.x = f2bf(acc[i][j][0]); p.y = f2bf(acc[i][j][1]);
        p.z = f2bf(acc[i][j][2]); p.w = f2bf(acc[i][j][3]);
        *(ushort4*)(vtb + ((size_t)(b * NH + h) * HD + d) * SS + s0) = p;
      }
    }
  }
}

// ---------------------------------------------------------------- flash attention
// Round-11 exact (passed many rounds, ~54 µs): S^T = K*Q^T core, in-register P.
__device__ __forceinline__ int co(int row, int c16) {   // ushort offset of (row, chunk)
  return row * 64 + ((c16 ^ ((row ^ (row >> 3)) & 7)) << 3);
}

__global__ __launch_bounds__(256, 2) void attn_kernel(const unsigned short* __restrict__ qg,
                                                      const unsigned short* __restrict__ kg,
                                                      const unsigned short* __restrict__ vtg,
                                                      unsigned short* __restrict__ og) {
  __shared__ __attribute__((aligned(16))) unsigned short Sall[16384];
  unsigned short* Qs = Sall;            // 128 rows x 64
  unsigned short* Ks = Sall + 8192;     //  64 rows x 64 (keys x d)
  unsigned short* Vs = Sall + 12288;    //  64 rows x 64 ([d][key])

  const int tid = threadIdx.x;
  const int w = tid >> 6, lane = tid & 63;
  const int hl = lane >> 5, c = lane & 31;
  const int q0 = blockIdx.x * 128;
  const int head = blockIdx.y, b = blockIdx.z;

  const unsigned short* qbase = qg + (size_t)(b * NH + head) * SS * HD;
  const unsigned short* kbase = kg + (size_t)(b * NH + head) * SS * HD;
  const unsigned short* vbase = vtg + (size_t)(b * NH + head) * HD * SS;

  {
    int row = tid >> 3, cc = tid & 7;
#pragma unroll
    for (int s = 0; s < 4; s++)
      *(uint4*)(Qs + co(row + 32 * s, cc)) =
          *(const uint4*)(qbase + (size_t)(q0 + row + 32 * s) * HD + cc * 8);
  }

  const int frow = tid >> 3, fc = tid & 7;
  uint4 k0r = *(const uint4*)(kbase + (size_t)frow * HD + fc * 8);
  uint4 k1r = *(const uint4*)(kbase + (size_t)(frow + 32) * HD + fc * 8);
  uint4 v0r = *(const uint4*)(vbase + (size_t)frow * SS + fc * 8);
  uint4 v1r = *(const uint4*)(vbase + (size_t)(frow + 32) * SS + fc * 8);

  floatx16 oacc0, oacc1, lacc;
#pragma unroll
  for (int i = 0; i < 16; i++) { oacc0[i] = 0.f; oacc1[i] = 0.f; lacc[i] = 0.f; }

  short8 ones;
#pragma unroll
  for (int i = 0; i < 8; i++) ones[i] = (short)0x3F80;   // bf16 1.0

  short8 qa[4];

  for (int kt = 0; kt < SS; kt += 64) {
    __syncthreads();
    *(uint4*)(Ks + co(frow, fc)) = k0r;
    *(uint4*)(Ks + co(frow + 32, fc)) = k1r;
    *(uint4*)(Vs + co(frow, fc)) = v0r;
    *(uint4*)(Vs + co(frow + 32, fc)) = v1r;
    if (kt + 64 < SS) {
      k0r = *(const uint4*)(kbase + (size_t)(kt + 64 + frow) * HD + fc * 8);
      k1r = *(const uint4*)(kbase + (size_t)(kt + 96 + frow) * HD + fc * 8);
      v0r = *(const uint4*)(vbase + (size_t)frow * SS + kt + 64 + fc * 8);
      v1r = *(const uint4*)(vbase + (size_t)(frow + 32) * SS + kt + 64 + fc * 8);
    }
    __syncthreads();

    if (kt == 0) {
#pragma unroll
      for (int ks = 0; ks < 4; ks++)
        qa[ks] = *(const short8*)(Qs + co(w * 32 + c, ks * 2 + hl));
    }

    floatx16 sacc0, sacc1;
#pragma unroll
    for (int i = 0; i < 16; i++) { sacc0[i] = 0.f; sacc1[i] = 0.f; }
#pragma unroll
    for (int ks = 0; ks < 4; ks++) {
      short8 ka0 = *(const short8*)(Ks + co(c, ks * 2 + hl));
      short8 ka1 = *(const short8*)(Ks + co(32 + c, ks * 2 + hl));
      sacc0 = MFMA32(ka0, qa[ks], sacc0);
      sacc1 = MFMA32(ka1, qa[ks], sacc1);
    }

    short8 pb[4];
#pragma unroll
    for (int kb = 0; kb < 4; kb++) {
      const floatx16& s = (kb < 2) ? sacc0 : sacc1;
      int base = (kb & 1) * 8;
      unsigned int u0 = pack2e(fexp2(s[base + 0]), fexp2(s[base + 1]));
      unsigned int u1 = pack2e(fexp2(s[base + 2]), fexp2(s[base + 3]));
      unsigned int u2 = pack2e(fexp2(s[base + 4]), fexp2(s[base + 5]));
      unsigned int u3 = pack2e(fexp2(s[base + 6]), fexp2(s[base + 7]));
      uint4 u = {u0, u1, u2, u3};
      pb[kb] = __builtin_bit_cast(short8, u);
    }

#pragma unroll
    for (int kb = 0; kb < 4; kb++) {
      uint2 lo0 = *(const uint2*)(Vs + co(c, 2 * kb) + 4 * hl);
      uint2 hi0 = *(const uint2*)(Vs + co(c, 2 * kb + 1) + 4 * hl);
      uint4 a0 = {lo0.x, lo0.y, hi0.x, hi0.y};
      short8 va0 = __builtin_bit_cast(short8, a0);
      uint2 lo1 = *(const uint2*)(Vs + co(32 + c, 2 * kb) + 4 * hl);
      uint2 hi1 = *(const uint2*)(Vs + co(32 + c, 2 * kb + 1) + 4 * hl);
      uint4 a1 = {lo1.x, lo1.y, hi1.x, hi1.y};
      short8 va1 = __builtin_bit_cast(short8, a1);
      oacc0 = MFMA32(va0, pb[kb], oacc0);
      oacc1 = MFMA32(va1, pb[kb], oacc1);
      lacc = MFMA32(ones, pb[kb], lacc);
    }
  }

  __syncthreads();
  unsigned short* sc = Sall + w * 2176;
  float inv = 1.0f / lacc[0];
#pragma unroll
  for (int t = 0; t < 8; t++) {
    int d0 = ((2 * t) & 3) + 8 * (t >> 1) + 4 * hl;
    *(unsigned int*)(sc + c * 68 + d0) = pack2e(oacc0[2 * t] * inv, oacc0[2 * t + 1] * inv);
    *(unsigned int*)(sc + c * 68 + 32 + d0) = pack2e(oacc1[2 * t] * inv, oacc1[2 * t + 1] * inv);
  }
  {
    int ql = lane >> 1, hf = lane & 1;
    size_t row = (size_t)(b * SS + q0 + w * 32 + ql);
    unsigned short* dst = og + row * HH + head * 64 + hf * 32;
    const unsigned short* srcp = sc + ql * 68 + hf * 32;
#pragma unroll
    for (int s = 0; s < 4; s++) {
      uint2 a = *(const uint2*)(srcp + s * 8);
      uint2 bq = *(const uint2*)(srcp + s * 8 + 4);
      uint4 v = {a.x, a.y, bq.x, bq.y};
      *(uint4*)(dst + s * 8) = v;
    }
  }
}

// ---------------------------------------------------------------- out projection (dbuf DMA)
// 128m x 64n tiles; A + pre-cast B via global_load_lds, same 2-phase pipeline,
// counted vmcnt(3) (3 DMA loads per tile).
__global__ __launch_bounds__(256) void gemm_out_dma(const unsigned short* __restrict__ A,
                                                    const unsigned short* __restrict__ Wb,
                                                    float* __restrict__ C) {
  __shared__ __attribute__((aligned(16))) unsigned short As[2][128 * 32];  // 2 x 8 KB
  __shared__ __attribute__((aligned(16))) unsigned short Bs[2][64 * 32];   // 2 x 4 KB
  const int tid = threadIdx.x;
  const int wave = tid >> 6, lane = tid & 63;
  const int quad = lane >> 4, lc = lane & 15;
  const int m0 = blockIdx.y * 128, n0 = blockIdx.x * 64;
  const int wm = (wave >> 1) * 64, wn = (wave & 1) * 32;
  const int sr = tid >> 2, sc = (tid & 3) * 8;

  floatx4 acc[4][2];
#pragma unroll
  for (int i = 0; i < 4; i++)
#pragma unroll
    for (int j = 0; j < 2; j++) acc[i][j] = (floatx4){0.f, 0.f, 0.f, 0.f};

  const unsigned short* Axp = A + (size_t)(m0 + sr) * KK + sc;
  const unsigned short* Bxp = Wb + (size_t)(n0 + sr) * KK + sc;

#define STAGEO(buf, k0)                                               \
  do {                                                                \
    gload_lds16(Axp + (k0), &As[buf][wave * 512]);                    \
    gload_lds16(Axp + (size_t)64 * KK + (k0), &As[buf][wave * 512 + 2048]); \
    gload_lds16(Bxp + (k0), &Bs[buf][wave * 512]);                    \
  } while (0)

  STAGEO(0, 0);

  const int NIT = KK / 32;
  for (int it = 0; it < NIT; ++it) {
    const int cb = it & 1;
    if (it + 1 < NIT) {
      STAGEO(cb ^ 1, (it + 1) * 32);
      asm volatile("s_waitcnt vmcnt(3)" ::: "memory");
    } else {
      asm volatile("s_waitcnt vmcnt(0)" ::: "memory");
    }
    __builtin_amdgcn_s_barrier();
    __builtin_amdgcn_sched_barrier(0);
    short8 af[4], bfr[2];
#pragma unroll
    for (int i = 0; i < 4; i++)
      af[i] = *(const short8*)(&As[cb][(wm + i * 16 + lc) * 32 + quad * 8]);
#pragma unroll
    for (int j = 0; j < 2; j++)
      bfr[j] = *(const short8*)(&Bs[cb][(wn + j * 16 + lc) * 32 + quad * 8]);
#pragma unroll
    for (int i = 0; i < 4; i++)
#pragma unroll
      for (int j = 0; j < 2; j++) acc[i][j] = MFMA16(af[i], bfr[j], acc[i][j]);
    __builtin_amdgcn_sched_barrier(0);
    __builtin_amdgcn_s_barrier();
  }
#undef STAGEO

#pragma unroll
  for (int i = 0; i < 4; i++)
#pragma unroll
    for (int j = 0; j < 2; j++) {
      int m = m0 + wm + i * 16 + quad * 4;
      int n = n0 + wn + j * 16 + lc;
#pragma unroll
      for (int r = 0; r < 4; r++) C[(size_t)(m + r) * HH + n] = acc[i][j][r];
    }
}

// ---------------------------------------------------------------- launch
extern "C" void kernel_launch(void* const* d_in, const int* in_sizes, int n_in,
                              void* d_out, int out_size, void* d_ws, size_t ws_size,
                              hipStream_t stream) {
  const float* x = (const float*)d_in[0];        // [2,2048,1024]
  const float* qkv_w = (const float*)d_in[1];    // [3072,1024]
  const float* out_w = (const float*)d_in[2];    // [1024,1024]
  float* out = (float*)d_out;                    // [2,2048,1024] fp32

  char* ws = (char*)d_ws;
  unsigned short* qb  = (unsigned short*)(ws + 0);          //  8 MiB [B][h][S][64]
  unsigned short* kb  = (unsigned short*)(ws + 8388608);    //  8 MiB [B][h][S][64]
  unsigned short* vtb = (unsigned short*)(ws + 16777216);   //  8 MiB [B][h][64][S]
  unsigned short* xb  = (unsigned short*)(ws + 25165824);   //  8 MiB bf16 x (dead after gemm_qkv)
  unsigned short* ao  = xb;                                 //  aliases xb (attn writes after)
  unsigned short* wob = qb;                                 //  bf16 out_w, aliases qb (dead after attn)

  const bool big = ws_size >= 40ull * 1024 * 1024;
  unsigned short* w1b = big ? (unsigned short*)(ws + 33554432) : nullptr;  // 6 MiB bf16 qkv_w

  if (big) {
    cast_xw<<<dim3((MM * KK + N_QKV * KK) / 2048), dim3(256), 0, stream>>>(x, qkv_w, xb, w1b);
    gemm_qkv_dma<<<dim3(N_QKV / 128, MM / 128), dim3(256), 0, stream>>>(xb, w1b, qb, kb, vtb);
  } else {
    cast_g<<<dim3(MM * KK / 2048), dim3(256), 0, stream>>>(x, xb);
    gemm_qkv_f32<<<dim3(N_QKV / 128, MM / 128), dim3(256), 0, stream>>>(xb, qkv_w, qb, kb, vtb);
  }
  attn_kernel<<<dim3(SS / 128, NH, BB), dim3(256), 0, stream>>>(qb, kb, vtb, ao);
  cast_g<<<dim3(HH * KK / 2048), dim3(256), 0, stream>>>(out_w, wob);
  gemm_out_dma<<<dim3(HH / 64, MM / 128), dim3(256), 0, stream>>>(ao, wob, out);
}

// Round 4
// 182.073 us; speedup vs baseline: 1.0968x; 1.0578x over previous
//
#include <hip/hip_runtime.h>
#include <hip/hip_bf16.h>

// Shapes (fixed by the reference)
#define BB 2
#define SS 2048
#define HH 1024
#define NH 16
#define HD 64
#define MM (BB * SS)          // 4096 rows of x
#define N_QKV (3 * HH)        // 3072
#define KK HH                 // 1024

typedef __attribute__((ext_vector_type(8))) short short8;
typedef __attribute__((ext_vector_type(4))) float floatx4;
typedef __attribute__((ext_vector_type(16))) float floatx16;

#define MFMA16(a, b, c) __builtin_amdgcn_mfma_f32_16x16x32_bf16(a, b, c, 0, 0, 0)
#define MFMA32(a, b, c) __builtin_amdgcn_mfma_f32_32x32x16_bf16(a, b, c, 0, 0, 0)

__device__ __forceinline__ unsigned short f2bf(float f) {
  unsigned int u = __builtin_bit_cast(unsigned int, f);
  u += 0x7FFFu + ((u >> 16) & 1u);   // RNE
  return (unsigned short)(u >> 16);
}

// Raw v_exp_f32 — scores are bounded, underflow-to-0 harmless.
__device__ __forceinline__ float fexp2(float x) {
#if __has_builtin(__builtin_amdgcn_exp2f)
  return __builtin_amdgcn_exp2f(x);
#else
  float r; asm("v_exp_f32 %0, %1" : "=v"(r) : "v"(x)); return r;
#endif
}

// pack2 WITHOUT rounding fixup for exp results (attn path) — keep bit-identical
// to the passing kernels.
__device__ __forceinline__ unsigned int pack2e(float lo, float hi) {
  unsigned int a = __builtin_bit_cast(unsigned int, lo) + 0x8000u;
  unsigned int b = __builtin_bit_cast(unsigned int, hi) + 0x8000u;
  return __builtin_amdgcn_perm(b, a, 0x07060302u);
}

// v_cvt_pk_bf16_f32: 2 f32 -> packed 2x bf16, RNE — 1 VALU. Inline asm (m240).
__device__ __forceinline__ unsigned int cvtpk(float lo, float hi) {
  unsigned int r;
  asm("v_cvt_pk_bf16_f32 %0, %1, %2" : "=v"(r) : "v"(lo), "v"(hi));
  return r;
}

// convert 8 f32 (two float4) -> 8 bf16 packed in a uint4 (RNE)
__device__ __forceinline__ uint4 cvt8pk(float4 lo, float4 hi) {
  uint4 u;
  u.x = cvtpk(lo.x, lo.y);
  u.y = cvtpk(lo.z, lo.w);
  u.z = cvtpk(hi.x, hi.y);
  u.w = cvtpk(hi.z, hi.w);
  return u;
}

// Async global->LDS DMA, 16 B per lane. LDS dest must be the WAVE-UNIFORM base;
// HW writes base + lane*16 (m104). Global source is per-lane.
__device__ __forceinline__ void gload_lds16(const void* g, void* l) {
  __builtin_amdgcn_global_load_lds((const __attribute__((address_space(1))) void*)g,
                                   (__attribute__((address_space(3))) void*)l,
                                   16, 0, 0);
}

// ---------------------------------------------------------------- casts
// Fused f32 -> bf16 for x / qkv_w / out_w (RNE, same rounding as old in-GEMM
// pack2). Grid = 4096 blocks exactly covers the three regions.
__global__ __launch_bounds__(256) void cast_all(const float* __restrict__ x,
                                                const float* __restrict__ w1,
                                                const float* __restrict__ w2,
                                                unsigned short* __restrict__ xb,
                                                unsigned short* __restrict__ w1b,
                                                unsigned short* __restrict__ w2b) {
  const int NX = MM * KK / 8;          // 524288
  const int NW1 = N_QKV * KK / 8;      // 393216
  int i = blockIdx.x * 256 + threadIdx.x;
  const float* s; unsigned short* d; int o;
  if (i < NX)            { s = x;  d = xb;  o = i; }
  else if (i < NX + NW1) { s = w1; d = w1b; o = i - NX; }
  else                   { s = w2; d = w2b; o = i - (NX + NW1); }
  float4 lo = *(const float4*)(s + (size_t)o * 8);
  float4 hi = *(const float4*)(s + (size_t)o * 8 + 4);
  *(uint4*)(d + (size_t)o * 8) = cvt8pk(lo, hi);
}

// Generic single-tensor cast (small-ws fallback path).
__global__ __launch_bounds__(256) void cast_g(const float* __restrict__ s,
                                              unsigned short* __restrict__ d) {
  size_t i = (size_t)blockIdx.x * 256 + threadIdx.x;
  float4 lo = *(const float4*)(s + i * 8);
  float4 hi = *(const float4*)(s + i * 8 + 4);
  *(uint4*)(d + i * 8) = cvt8pk(lo, hi);
}

// ---------------------------------------------------------------- QKV GEMM (BK=64 dbuf DMA)
// 128x128 tile, BK=64: 32 MFMA per barrier-pair (2x round-3's amortization).
// LDS XOR-swizzle (chunk ^ (row&7)) applied as pre-swizzled GLOBAL source +
// swizzled ds_read (both-sides involution; gload_lds writes stay linear).
// XCD-aware 1D grid swizzle (768 blocks = 96/XCD, n-major within XCD).
__global__ __launch_bounds__(256) void gemm_qkv_dma(const unsigned short* __restrict__ Xb,
                                                    const unsigned short* __restrict__ Wb,
                                                    unsigned short* __restrict__ qb,
                                                    unsigned short* __restrict__ kb,
                                                    unsigned short* __restrict__ vtb) {
  __shared__ __attribute__((aligned(16))) unsigned short As[2][128 * 64];  // 2 x 16 KB
  __shared__ __attribute__((aligned(16))) unsigned short Bs[2][128 * 64];  // 2 x 16 KB
  const int tid = threadIdx.x;
  const int wave = tid >> 6, lane = tid & 63;
  const int quad = lane >> 4, lc = lane & 15;
  const int wg = (blockIdx.x & 7) * 96 + (blockIdx.x >> 3);   // bijective: 768 % 8 == 0
  const int m0 = (wg / 24) * 128, n0 = (wg % 24) * 128;
  const int wm = (wave >> 1) * 64, wn = (wave & 1) * 64;

  floatx4 acc[4][4];
#pragma unroll
  for (int i = 0; i < 4; i++)
#pragma unroll
    for (int j = 0; j < 4; j++) acc[i][j] = (floatx4){0.f, 0.f, 0.f, 0.f};

  // Staging: round g covers rows [g*32, g*32+32); wave covers 8 rows of it.
  // Lane l -> row (wave*8 + l>>3), chunk l&7. Source chunk pre-XORed by row&7
  // (= l>>3 here) so LDS slot (row, j) holds global chunk j ^ (row&7).
  const int srow = lane >> 3;                  // row & 7
  const int schk = (lane & 7) ^ srow;          // pre-swizzled source chunk
  const unsigned short* Ab = Xb + (size_t)(m0 + wave * 8 + srow) * KK + schk * 8;
  const unsigned short* Bb = Wb + (size_t)(n0 + wave * 8 + srow) * KK + schk * 8;

#define STAGEQ(buf, k0)                                                          \
  do {                                                                           \
    _Pragma("unroll")                                                            \
    for (int g = 0; g < 4; g++) {                                                \
      gload_lds16(Ab + (size_t)g * 32 * KK + (k0), &As[buf][(g * 32 + wave * 8) * 64]); \
      gload_lds16(Bb + (size_t)g * 32 * KK + (k0), &Bs[buf][(g * 32 + wave * 8) * 64]); \
    }                                                                            \
  } while (0)

  STAGEQ(0, 0);   // prologue: 8 loads for tile 0 in flight

  const int NIT = KK / 64;   // 16
  for (int it = 0; it < NIT; ++it) {
    const int cb = it & 1;
    if (it + 1 < NIT) {
      STAGEQ(cb ^ 1, (it + 1) * 64);                   // next tile first (8 loads)
      asm volatile("s_waitcnt vmcnt(8)" ::: "memory"); // tile it landed; next 8 in flight
    } else {
      asm volatile("s_waitcnt vmcnt(0)" ::: "memory");
    }
    __builtin_amdgcn_s_barrier();                      // tile it visible to all waves
    __builtin_amdgcn_sched_barrier(0);
    __builtin_amdgcn_s_setprio(1);
#pragma unroll
    for (int kk = 0; kk < 2; kk++) {
      short8 af[4], bfr[4];
#pragma unroll
      for (int i = 0; i < 4; i++) {
        const int cs = ((kk * 4 + quad) ^ (lc & 7)) << 3;   // swizzled chunk, ushorts
        af[i]  = *(const short8*)(&As[cb][(wm + i * 16 + lc) * 64 + cs]);
        bfr[i] = *(const short8*)(&Bs[cb][(wn + i * 16 + lc) * 64 + cs]);
      }
#pragma unroll
      for (int i = 0; i < 4; i++)
#pragma unroll
        for (int j = 0; j < 4; j++) acc[i][j] = MFMA16(af[i], bfr[j], acc[i][j]);
    }
    __builtin_amdgcn_s_setprio(0);
    __builtin_amdgcn_sched_barrier(0);
    __builtin_amdgcn_s_barrier();                      // reads of buf cb done
  }
#undef STAGEQ

  const float QSCALE = 0.125f * 1.44269504f;   // 1/sqrt(64) * log2(e)
#pragma unroll
  for (int j = 0; j < 4; j++) {
    int n = n0 + wn + j * 16 + lc;
#pragma unroll
    for (int i = 0; i < 4; i++) {
      int mbase = m0 + wm + i * 16 + quad * 4;
      int b = mbase >> 11;
      int s0 = mbase & 2047;
      if (n < HH) {                 // Q, pre-scale
        int h = n >> 6, d = n & 63;
#pragma unroll
        for (int r = 0; r < 4; r++)
          qb[(((size_t)(b * NH + h) * SS + s0 + r) * HD) + d] = f2bf(acc[i][j][r] * QSCALE);
      } else if (n < 2 * HH) {      // K
        int n2 = n - HH; int h = n2 >> 6, d = n2 & 63;
#pragma unroll
        for (int r = 0; r < 4; r++)
          kb[(((size_t)(b * NH + h) * SS + s0 + r) * HD) + d] = f2bf(acc[i][j][r]);
      } else {                      // V -> transposed [b][h][d][s]
        int n2 = n - 2 * HH; int h = n2 >> 6, d = n2 & 63;
        ushort4 p;
        p.x = f2bf(acc[i][j][0]); p.y = f2bf(acc[i][j][1]);
        p.z = f2bf(acc[i][j][2]); p.w = f2bf(acc[i][j][3]);
        *(ushort4*)(vtb + ((size_t)(b * NH + h) * HD + d) * SS + s0) = p;
      }
    }
  }
}

// ---------------------------------------------------------------- QKV GEMM (f32-B fallback)
// Small-ws path only. Round-2 structure (passed): A via DMA, B reg-staged f32.
__global__ __launch_bounds__(256) void gemm_qkv_f32(const unsigned short* __restrict__ Xb,
                                                    const float* __restrict__ Wf,
                                                    unsigned short* __restrict__ qb,
                                                    unsigned short* __restrict__ kb,
                                                    unsigned short* __restrict__ vtb) {
  __shared__ __attribute__((aligned(16))) unsigned short As[128 * 32];
  __shared__ __attribute__((aligned(16))) unsigned short Bs[128 * 32];
  const int tid = threadIdx.x;
  const int wave = tid >> 6, lane = tid & 63;
  const int quad = lane >> 4, lc = lane & 15;
  const int m0 = blockIdx.y * 128, n0 = blockIdx.x * 128;
  const int wm = (wave >> 1) * 64, wn = (wave & 1) * 64;
  const int sr = tid >> 2, sc = (tid & 3) * 8;

  floatx4 acc[4][4];
#pragma unroll
  for (int i = 0; i < 4; i++)
#pragma unroll
    for (int j = 0; j < 4; j++) acc[i][j] = (floatx4){0.f, 0.f, 0.f, 0.f};

  const unsigned short* Axp = Xb + (size_t)(m0 + sr) * KK + sc;
  unsigned short* AsD = As + wave * 512;
  const float* Bg = Wf + (size_t)(n0 + sr) * KK + sc;
  unsigned short* BsW = Bs + wave * 512 + lane * 8;
  float4 b0l = *(const float4*)(Bg),                    b0h = *(const float4*)(Bg + 4);
  float4 b1l = *(const float4*)(Bg + (size_t)64 * KK),  b1h = *(const float4*)(Bg + (size_t)64 * KK + 4);

  for (int it = 0; it < KK / 32; ++it) {
    const int k0 = it * 32;
    __syncthreads();
    gload_lds16(Axp + k0, AsD);
    gload_lds16(Axp + (size_t)64 * KK + k0, AsD + 2048);
    *(uint4*)(BsW) = cvt8pk(b0l, b0h);
    *(uint4*)(BsW + 2048) = cvt8pk(b1l, b1h);
    if (it + 1 < KK / 32) {
      b0l = *(const float4*)(Bg + k0 + 32);                    b0h = *(const float4*)(Bg + k0 + 36);
      b1l = *(const float4*)(Bg + k0 + 32 + (size_t)64 * KK);  b1h = *(const float4*)(Bg + k0 + 36 + (size_t)64 * KK);
    }
    __syncthreads();
    short8 af[4], bfr[4];
#pragma unroll
    for (int i = 0; i < 4; i++) {
      af[i]  = *(const short8*)(As + (wm + i * 16 + lc) * 32 + quad * 8);
      bfr[i] = *(const short8*)(Bs + (wn + i * 16 + lc) * 32 + quad * 8);
    }
#pragma unroll
    for (int i = 0; i < 4; i++)
#pragma unroll
      for (int j = 0; j < 4; j++) acc[i][j] = MFMA16(af[i], bfr[j], acc[i][j]);
  }

  const float QSCALE = 0.125f * 1.44269504f;
#pragma unroll
  for (int j = 0; j < 4; j++) {
    int n = n0 + wn + j * 16 + lc;
#pragma unroll
    for (int i = 0; i < 4; i++) {
      int mbase = m0 + wm + i * 16 + quad * 4;
      int b = mbase >> 11;
      int s0 = mbase & 2047;
      if (n < HH) {
        int h = n >> 6, d = n & 63;
#pragma unroll
        for (int r = 0; r < 4; r++)
          qb[(((size_t)(b * NH + h) * SS + s0 + r) * HD) + d] = f2bf(acc[i][j][r] * QSCALE);
      } else if (n < 2 * HH) {
        int n2 = n - HH; int h = n2 >> 6, d = n2 & 63;
#pragma unroll
        for (int r = 0; r < 4; r++)
          kb[(((size_t)(b * NH + h) * SS + s0 + r) * HD) + d] = f2bf(acc[i][j][r]);
      } else {
        int n2 = n - 2 * HH; int h = n2 >> 6, d = n2 & 63;
        ushort4 p;
        p.x = f2bf(acc[i][j][0]); p.y = f2bf(acc[i][j][1]);
        p.z = f2bf(acc[i][j][2]); p.w = f2bf(acc[i][j][3]);
        *(ushort4*)(vtb + ((size_t)(b * NH + h) * HD + d) * SS + s0) = p;
      }
    }
  }
}

// ---------------------------------------------------------------- flash attention
// Round-11 exact core (passed many rounds); this round adds only s_setprio
// around the MFMA clusters (T5, m191: +4-7% on attn; no correctness impact).
__device__ __forceinline__ int co(int row, int c16) {   // ushort offset of (row, chunk)
  return row * 64 + ((c16 ^ ((row ^ (row >> 3)) & 7)) << 3);
}

__global__ __launch_bounds__(256, 2) void attn_kernel(const unsigned short* __restrict__ qg,
                                                      const unsigned short* __restrict__ kg,
                                                      const unsigned short* __restrict__ vtg,
                                                      unsigned short* __restrict__ og) {
  __shared__ __attribute__((aligned(16))) unsigned short Sall[16384];
  unsigned short* Qs = Sall;            // 128 rows x 64
  unsigned short* Ks = Sall + 8192;     //  64 rows x 64 (keys x d)
  unsigned short* Vs = Sall + 12288;    //  64 rows x 64 ([d][key])

  const int tid = threadIdx.x;
  const int w = tid >> 6, lane = tid & 63;
  const int hl = lane >> 5, c = lane & 31;
  const int q0 = blockIdx.x * 128;
  const int head = blockIdx.y, b = blockIdx.z;

  const unsigned short* qbase = qg + (size_t)(b * NH + head) * SS * HD;
  const unsigned short* kbase = kg + (size_t)(b * NH + head) * SS * HD;
  const unsigned short* vbase = vtg + (size_t)(b * NH + head) * HD * SS;

  {
    int row = tid >> 3, cc = tid & 7;
#pragma unroll
    for (int s = 0; s < 4; s++)
      *(uint4*)(Qs + co(row + 32 * s, cc)) =
          *(const uint4*)(qbase + (size_t)(q0 + row + 32 * s) * HD + cc * 8);
  }

  const int frow = tid >> 3, fc = tid & 7;
  uint4 k0r = *(const uint4*)(kbase + (size_t)frow * HD + fc * 8);
  uint4 k1r = *(const uint4*)(kbase + (size_t)(frow + 32) * HD + fc * 8);
  uint4 v0r = *(const uint4*)(vbase + (size_t)frow * SS + fc * 8);
  uint4 v1r = *(const uint4*)(vbase + (size_t)(frow + 32) * SS + fc * 8);

  floatx16 oacc0, oacc1, lacc;
#pragma unroll
  for (int i = 0; i < 16; i++) { oacc0[i] = 0.f; oacc1[i] = 0.f; lacc[i] = 0.f; }

  short8 ones;
#pragma unroll
  for (int i = 0; i < 8; i++) ones[i] = (short)0x3F80;   // bf16 1.0

  short8 qa[4];

  for (int kt = 0; kt < SS; kt += 64) {
    __syncthreads();
    *(uint4*)(Ks + co(frow, fc)) = k0r;
    *(uint4*)(Ks + co(frow + 32, fc)) = k1r;
    *(uint4*)(Vs + co(frow, fc)) = v0r;
    *(uint4*)(Vs + co(frow + 32, fc)) = v1r;
    if (kt + 64 < SS) {
      k0r = *(const uint4*)(kbase + (size_t)(kt + 64 + frow) * HD + fc * 8);
      k1r = *(const uint4*)(kbase + (size_t)(kt + 96 + frow) * HD + fc * 8);
      v0r = *(const uint4*)(vbase + (size_t)frow * SS + kt + 64 + fc * 8);
      v1r = *(const uint4*)(vbase + (size_t)(frow + 32) * SS + kt + 64 + fc * 8);
    }
    __syncthreads();

    if (kt == 0) {
#pragma unroll
      for (int ks = 0; ks < 4; ks++)
        qa[ks] = *(const short8*)(Qs + co(w * 32 + c, ks * 2 + hl));
    }

    floatx16 sacc0, sacc1;
#pragma unroll
    for (int i = 0; i < 16; i++) { sacc0[i] = 0.f; sacc1[i] = 0.f; }
    __builtin_amdgcn_s_setprio(1);
#pragma unroll
    for (int ks = 0; ks < 4; ks++) {
      short8 ka0 = *(const short8*)(Ks + co(c, ks * 2 + hl));
      short8 ka1 = *(const short8*)(Ks + co(32 + c, ks * 2 + hl));
      sacc0 = MFMA32(ka0, qa[ks], sacc0);
      sacc1 = MFMA32(ka1, qa[ks], sacc1);
    }
    __builtin_amdgcn_s_setprio(0);

    short8 pb[4];
#pragma unroll
    for (int kb = 0; kb < 4; kb++) {
      const floatx16& s = (kb < 2) ? sacc0 : sacc1;
      int base = (kb & 1) * 8;
      unsigned int u0 = pack2e(fexp2(s[base + 0]), fexp2(s[base + 1]));
      unsigned int u1 = pack2e(fexp2(s[base + 2]), fexp2(s[base + 3]));
      unsigned int u2 = pack2e(fexp2(s[base + 4]), fexp2(s[base + 5]));
      unsigned int u3 = pack2e(fexp2(s[base + 6]), fexp2(s[base + 7]));
      uint4 u = {u0, u1, u2, u3};
      pb[kb] = __builtin_bit_cast(short8, u);
    }

    __builtin_amdgcn_s_setprio(1);
#pragma unroll
    for (int kb = 0; kb < 4; kb++) {
      uint2 lo0 = *(const uint2*)(Vs + co(c, 2 * kb) + 4 * hl);
      uint2 hi0 = *(const uint2*)(Vs + co(c, 2 * kb + 1) + 4 * hl);
      uint4 a0 = {lo0.x, lo0.y, hi0.x, hi0.y};
      short8 va0 = __builtin_bit_cast(short8, a0);
      uint2 lo1 = *(const uint2*)(Vs + co(32 + c, 2 * kb) + 4 * hl);
      uint2 hi1 = *(const uint2*)(Vs + co(32 + c, 2 * kb + 1) + 4 * hl);
      uint4 a1 = {lo1.x, lo1.y, hi1.x, hi1.y};
      short8 va1 = __builtin_bit_cast(short8, a1);
      oacc0 = MFMA32(va0, pb[kb], oacc0);
      oacc1 = MFMA32(va1, pb[kb], oacc1);
      lacc = MFMA32(ones, pb[kb], lacc);
    }
    __builtin_amdgcn_s_setprio(0);
  }

  __syncthreads();
  unsigned short* sc = Sall + w * 2176;
  float inv = 1.0f / lacc[0];
#pragma unroll
  for (int t = 0; t < 8; t++) {
    int d0 = ((2 * t) & 3) + 8 * (t >> 1) + 4 * hl;
    *(unsigned int*)(sc + c * 68 + d0) = pack2e(oacc0[2 * t] * inv, oacc0[2 * t + 1] * inv);
    *(unsigned int*)(sc + c * 68 + 32 + d0) = pack2e(oacc1[2 * t] * inv, oacc1[2 * t + 1] * inv);
  }
  {
    int ql = lane >> 1, hf = lane & 1;
    size_t row = (size_t)(b * SS + q0 + w * 32 + ql);
    unsigned short* dst = og + row * HH + head * 64 + hf * 32;
    const unsigned short* srcp = sc + ql * 68 + hf * 32;
#pragma unroll
    for (int s = 0; s < 4; s++) {
      uint2 a = *(const uint2*)(srcp + s * 8);
      uint2 bq = *(const uint2*)(srcp + s * 8 + 4);
      uint4 v = {a.x, a.y, bq.x, bq.y};
      *(uint4*)(dst + s * 8) = v;
    }
  }
}

// ---------------------------------------------------------------- out projection (BK=64 dbuf DMA)
// 128m x 64n tile, BK=64, same swizzle/pipeline as gemm_qkv_dma. 6 loads/tile
// -> vmcnt(6). XCD swizzle over 512 blocks (64/XCD, n-major).
__global__ __launch_bounds__(256) void gemm_out_dma(const unsigned short* __restrict__ A,
                                                    const unsigned short* __restrict__ Wb,
                                                    float* __restrict__ C) {
  __shared__ __attribute__((aligned(16))) unsigned short As[2][128 * 64];  // 2 x 16 KB
  __shared__ __attribute__((aligned(16))) unsigned short Bs[2][64 * 64];   // 2 x 8 KB
  const int tid = threadIdx.x;
  const int wave = tid >> 6, lane = tid & 63;
  const int quad = lane >> 4, lc = lane & 15;
  const int wg = (blockIdx.x & 7) * 64 + (blockIdx.x >> 3);   // 512 % 8 == 0
  const int m0 = (wg / 16) * 128, n0 = (wg % 16) * 64;
  const int wm = (wave >> 1) * 64, wn = (wave & 1) * 32;

  floatx4 acc[4][2];
#pragma unroll
  for (int i = 0; i < 4; i++)
#pragma unroll
    for (int j = 0; j < 2; j++) acc[i][j] = (floatx4){0.f, 0.f, 0.f, 0.f};

  const int srow = lane >> 3;
  const int schk = (lane & 7) ^ srow;
  const unsigned short* Ab = A  + (size_t)(m0 + wave * 8 + srow) * KK + schk * 8;
  const unsigned short* Bb = Wb + (size_t)(n0 + wave * 8 + srow) * KK + schk * 8;

#define STAGEO(buf, k0)                                                          \
  do {                                                                           \
    _Pragma("unroll")                                                            \
    for (int g = 0; g < 4; g++)                                                  \
      gload_lds16(Ab + (size_t)g * 32 * KK + (k0), &As[buf][(g * 32 + wave * 8) * 64]); \
    _Pragma("unroll")                                                            \
    for (int g = 0; g < 2; g++)                                                  \
      gload_lds16(Bb + (size_t)g * 32 * KK + (k0), &Bs[buf][(g * 32 + wave * 8) * 64]); \
  } while (0)

  STAGEO(0, 0);

  const int NIT = KK / 64;   // 16
  for (int it = 0; it < NIT; ++it) {
    const int cb = it & 1;
    if (it + 1 < NIT) {
      STAGEO(cb ^ 1, (it + 1) * 64);
      asm volatile("s_waitcnt vmcnt(6)" ::: "memory");
    } else {
      asm volatile("s_waitcnt vmcnt(0)" ::: "memory");
    }
    __builtin_amdgcn_s_barrier();
    __builtin_amdgcn_sched_barrier(0);
    __builtin_amdgcn_s_setprio(1);
#pragma unroll
    for (int kk = 0; kk < 2; kk++) {
      short8 af[4], bfr[2];
#pragma unroll
      for (int i = 0; i < 4; i++)
        af[i] = *(const short8*)(&As[cb][(wm + i * 16 + lc) * 64 + (((kk * 4 + quad) ^ (lc & 7)) << 3)]);
#pragma unroll
      for (int j = 0; j < 2; j++)
        bfr[j] = *(const short8*)(&Bs[cb][(wn + j * 16 + lc) * 64 + (((kk * 4 + quad) ^ (lc & 7)) << 3)]);
#pragma unroll
      for (int i = 0; i < 4; i++)
#pragma unroll
        for (int j = 0; j < 2; j++) acc[i][j] = MFMA16(af[i], bfr[j], acc[i][j]);
    }
    __builtin_amdgcn_s_setprio(0);
    __builtin_amdgcn_sched_barrier(0);
    __builtin_amdgcn_s_barrier();
  }
#undef STAGEO

#pragma unroll
  for (int i = 0; i < 4; i++)
#pragma unroll
    for (int j = 0; j < 2; j++) {
      int m = m0 + wm + i * 16 + quad * 4;
      int n = n0 + wn + j * 16 + lc;
#pragma unroll
      for (int r = 0; r < 4; r++) C[(size_t)(m + r) * HH + n] = acc[i][j][r];
    }
}

// ---------------------------------------------------------------- launch
extern "C" void kernel_launch(void* const* d_in, const int* in_sizes, int n_in,
                              void* d_out, int out_size, void* d_ws, size_t ws_size,
                              hipStream_t stream) {
  const float* x = (const float*)d_in[0];        // [2,2048,1024]
  const float* qkv_w = (const float*)d_in[1];    // [3072,1024]
  const float* out_w = (const float*)d_in[2];    // [1024,1024]
  float* out = (float*)d_out;                    // [2,2048,1024] fp32

  char* ws = (char*)d_ws;
  unsigned short* qb  = (unsigned short*)(ws + 0);          //  8 MiB [B][h][S][64]
  unsigned short* kb  = (unsigned short*)(ws + 8388608);    //  8 MiB [B][h][S][64]
  unsigned short* vtb = (unsigned short*)(ws + 16777216);   //  8 MiB [B][h][64][S]
  unsigned short* xb  = (unsigned short*)(ws + 25165824);   //  8 MiB bf16 x (dead after gemm_qkv)
  unsigned short* ao  = xb;                                 //  aliases xb (attn writes after)

  const bool big = ws_size >= 40ull * 1024 * 1024;
  unsigned short* w1b = big ? (unsigned short*)(ws + 33554432) : nullptr;  // 6 MiB bf16 qkv_w
  unsigned short* w2b = big ? (unsigned short*)(ws + 39845888) : nullptr;  // 2 MiB bf16 out_w

  if (big) {
    cast_all<<<dim3(4096), dim3(256), 0, stream>>>(x, qkv_w, out_w, xb, w1b, w2b);
    gemm_qkv_dma<<<dim3(768), dim3(256), 0, stream>>>(xb, w1b, qb, kb, vtb);
    attn_kernel<<<dim3(SS / 128, NH, BB), dim3(256), 0, stream>>>(qb, kb, vtb, ao);
    gemm_out_dma<<<dim3(512), dim3(256), 0, stream>>>(ao, w2b, out);
  } else {
    unsigned short* wob = qb;   // bf16 out_w, aliases qb (dead after attn)
    cast_g<<<dim3(MM * KK / 2048), dim3(256), 0, stream>>>(x, xb);
    gemm_qkv_f32<<<dim3(N_QKV / 128, MM / 128), dim3(256), 0, stream>>>(xb, qkv_w, qb, kb, vtb);
    attn_kernel<<<dim3(SS / 128, NH, BB), dim3(256), 0, stream>>>(qb, kb, vtb, ao);
    cast_g<<<dim3(HH * KK / 2048), dim3(256), 0, stream>>>(out_w, wob);
    gemm_out_dma<<<dim3(512), dim3(256), 0, stream>>>(ao, wob, out);
  }
}